// Round 4
// baseline (375.414 us; speedup 1.0000x reference)
//
#include <hip/hip_runtime.h>

#define FEAT 256
#define HID 128
#define NKEYS 2

typedef __bf16 bf16x8 __attribute__((ext_vector_type(8)));
typedef float f32x16 __attribute__((ext_vector_type(16)));

union Frag {
    bf16x8 v;
    unsigned u[4];
    uint4 q;
};

// async global->LDS DMA, 16 B per lane; LDS dest = base + lane*16
__device__ __forceinline__ void load_lds16(const float* g, void* l) {
    __builtin_amdgcn_global_load_lds(
        (const __attribute__((address_space(1))) unsigned int*)g,
        (__attribute__((address_space(3))) unsigned int*)l,
        16, 0, 0);
}

// pack two f32 (as uint bits) -> two bf16 (round-half-up) in one v_perm
__device__ __forceinline__ unsigned pack_bf16_u2(unsigned u0, unsigned u1) {
    u0 += 0x8000u;
    u1 += 0x8000u;
    return __builtin_amdgcn_perm(u1, u0, 0x07060302u);
}

// shifted softplus: softplus(x) - ln2
__device__ __forceinline__ float ssp(float x) {
    float sp = __logf(1.0f + __expf(x));
    sp = (x > 15.0f) ? x : sp;
    return sp - 0.69314718056f;
}

// largest m with off[m] <= g  (off[0]=0, off sorted, n_mols+1 entries)
__device__ __forceinline__ int find_mol(const int* __restrict__ off, int n_mols, int g) {
    int lo = 0, hi = n_mols;
    while (hi - lo > 1) {
        int mid = (lo + hi) >> 1;
        if (off[mid] <= g) lo = mid; else hi = mid;
    }
    return lo;
}

// Block 0: prefix-scan num_atoms (int32, falling back to int64 if the int32
// interpretation doesn't sum to n_atoms) + zero d_out.
// Blocks 1..256: pack W1 -> Bp bf16, layout Bp[c][k] (c = key*HID + j).
__global__ void prep_kernel(const void* __restrict__ num_atoms_raw,
                            const float* __restrict__ W1,
                            int n_mols, int n_atoms,
                            int* __restrict__ off,
                            unsigned short* __restrict__ Bp,
                            float* __restrict__ out, int out_n) {
    if (blockIdx.x > 0) {
        int idx = (blockIdx.x - 1) * 256 + threadIdx.x;   // 0..65535
        int c = idx >> 8;
        int k = idx & 255;
        int key = c >> 7, j = c & 127;
        float f = W1[(size_t)key * FEAT * HID + (size_t)k * HID + j];
        unsigned u = __float_as_uint(f);
        unsigned r = (u + 0x7FFFu + ((u >> 16) & 1u)) >> 16;   // RNE to bf16
        Bp[(size_t)c * FEAT + k] = (unsigned short)r;
        return;
    }
    // zero the output (atomically accumulated by gemm_fused)
    for (int i = threadIdx.x; i < out_n; i += 256) out[i] = 0.0f;

    __shared__ long long tsum[256];
    __shared__ int csum[257];
    __shared__ int mode_sh;
    int tid = threadIdx.x;
    const int* a32 = (const int*)num_atoms_raw;
    const long long* a64 = (const long long*)num_atoms_raw;
    int chunk = (n_mols + 255) >> 8;
    int lo = tid * chunk;
    if (lo > n_mols) lo = n_mols;
    int hi = lo + chunk;
    if (hi > n_mols) hi = n_mols;
    long long s = 0;
    for (int i = lo; i < hi; ++i) s += (long long)a32[i];
    tsum[tid] = s;
    __syncthreads();
    if (tid == 0) {
        long long t = 0;
        for (int i = 0; i < 256; ++i) t += tsum[i];
        mode_sh = (t == (long long)n_atoms) ? 0 : 1;
    }
    __syncthreads();
    int mode = mode_sh;
    if (mode) {                      // only touch int64 view if int32 failed
        s = 0;
        for (int i = lo; i < hi; ++i) s += a64[i];
        tsum[tid] = s;
    }
    csum[tid] = (int)tsum[tid];
    __syncthreads();
    if (tid == 0) {
        int run = 0;
        for (int i = 0; i < 256; ++i) { int v = csum[i]; csum[i] = run; run += v; }
    }
    __syncthreads();
    int run = csum[tid];
    for (int i = lo; i < hi; ++i) {
        off[i] = run;
        run += mode ? (int)a64[i] : a32[i];
    }
    if (hi >= n_mols) off[n_mols] = run;
}

// Fused: C = s_i @ B (bf16 MFMA, fp32 acc), +b1, shifted-softplus, .W2, +b2,
// segment-sum into out[key][mol] via atomics.
// Block: 256 threads = 4 waves; tile 64 rows x 256 cols; wave = 64x64.
// A staged f32 via global_load_lds DMA (16 x 1KB row-DMAs per wave, all in
// flight, NO VGPR destinations -> compiler cannot serialize). One barrier.
// Rows rotated by 16B group on the global side so strided frag reads are
// bank-balanced. f32->bf16 conversion at frag-read time.
__global__ __launch_bounds__(256, 2)
void gemm_fused(const float* __restrict__ A,
                const unsigned short* __restrict__ Bp,
                const float* __restrict__ b1,
                const float* __restrict__ W2,
                const float* __restrict__ b2,
                const int* __restrict__ off,
                float* __restrict__ out,
                int n_atoms, int n_mols) {
    // row r occupies ldsA[r*64 .. r*64+63] (16B units); unit slot s of row r
    // holds global group g = (s - r) & 63  (i.e. slot = (g + r) & 63)
    __shared__ uint4 ldsA[64 * 64];      // 64 KB
    __shared__ float part[4][64];        // [wn][row]
    __shared__ float molacc[NKEYS][4];

    const int tid  = threadIdx.x;
    const int lane = tid & 63;
    const int wn   = tid >> 6;           // 0..3
    const int l31  = lane & 31;
    const int half = lane >> 5;          // 0/1
    const int m0   = blockIdx.x * 64;

    // ---- DMA phase: wave wn stages rows wn*16 .. wn*16+15 (1 KB each)
    #pragma unroll
    for (int i = 0; i < 16; ++i) {
        const int r = wn * 16 + i;
        int grow = m0 + r;
        if (grow > n_atoms - 1) grow = n_atoms - 1;
        const float* gp = A + (size_t)grow * FEAT + (((lane - r) & 63) << 2);
        load_lds16(gp, (void*)&ldsA[r * 64]);
    }

    // ---- B prefetch for chunks 0,1 (L2-resident, hides behind DMA drain)
    const int c0 = wn * 64 + l31;
    const unsigned short* bb0 = Bp + (size_t)c0 * FEAT + half * 8;
    const unsigned short* bb1 = Bp + (size_t)(c0 + 32) * FEAT + half * 8;
    Frag bf0[2][4], bf1[2][4];
    #pragma unroll
    for (int s = 0; s < 2; ++s)
        #pragma unroll
        for (int j = 0; j < 4; ++j) {
            bf0[s][j].q = *(const uint4*)(bb0 + s * 64 + j * 16);
            bf1[s][j].q = *(const uint4*)(bb1 + s * 64 + j * 16);
        }

    __syncthreads();                     // drains DMA vmcnt + barrier (once)

    // ---- compute phase: LDS f32 -> bf16 frags -> MFMA
    const int rb0 = l31 * 64;            // row l31
    const int rb1 = (l31 + 32) * 64;     // row l31+32

    f32x16 acc00 = 0.0f, acc01 = 0.0f, acc10 = 0.0f, acc11 = 0.0f;

    #pragma unroll
    for (int c = 0; c < 4; ++c) {
        const int slot = c & 1;
        #pragma unroll
        for (int j = 0; j < 4; ++j) {
            const int g0 = c * 16 + j * 4 + half * 2;   // 4-float group idx
            uint4 q0 = ldsA[rb0 + ((g0     + l31) & 63)];
            uint4 q1 = ldsA[rb0 + ((g0 + 1 + l31) & 63)];
            uint4 r0 = ldsA[rb1 + ((g0     + l31 + 32) & 63)];
            uint4 r1 = ldsA[rb1 + ((g0 + 1 + l31 + 32) & 63)];
            Frag a0, a1;
            a0.u[0] = pack_bf16_u2(q0.x, q0.y);
            a0.u[1] = pack_bf16_u2(q0.z, q0.w);
            a0.u[2] = pack_bf16_u2(q1.x, q1.y);
            a0.u[3] = pack_bf16_u2(q1.z, q1.w);
            a1.u[0] = pack_bf16_u2(r0.x, r0.y);
            a1.u[1] = pack_bf16_u2(r0.z, r0.w);
            a1.u[2] = pack_bf16_u2(r1.x, r1.y);
            a1.u[3] = pack_bf16_u2(r1.z, r1.w);
            acc00 = __builtin_amdgcn_mfma_f32_32x32x16_bf16(a0.v, bf0[slot][j].v, acc00, 0, 0, 0);
            acc01 = __builtin_amdgcn_mfma_f32_32x32x16_bf16(a0.v, bf1[slot][j].v, acc01, 0, 0, 0);
            acc10 = __builtin_amdgcn_mfma_f32_32x32x16_bf16(a1.v, bf0[slot][j].v, acc10, 0, 0, 0);
            acc11 = __builtin_amdgcn_mfma_f32_32x32x16_bf16(a1.v, bf1[slot][j].v, acc11, 0, 0, 0);
        }
        if (c + 2 < 4) {                 // refill this B slot with chunk c+2
            const int kb = (c + 2) * 64;
            #pragma unroll
            for (int j = 0; j < 4; ++j) {
                bf0[slot][j].q = *(const uint4*)(bb0 + kb + j * 16);
                bf1[slot][j].q = *(const uint4*)(bb1 + kb + j * 16);
            }
        }
    }

    if (tid < NKEYS * 4) molacc[tid >> 2][tid & 3] = 0.0f;

    float b1c0 = b1[c0], b1c1 = b1[c0 + 32];
    float w2c0 = W2[c0], w2c1 = W2[c0 + 32];

    // epilogue: act + .W2, column-reduce per row, stash in LDS
    #pragma unroll
    for (int rt = 0; rt < 2; ++rt) {
        const f32x16& Ac0 = rt ? acc10 : acc00;
        const f32x16& Ac1 = rt ? acc11 : acc01;
        #pragma unroll
        for (int r = 0; r < 16; ++r) {
            float t = ssp(Ac0[r] + b1c0) * w2c0 + ssp(Ac1[r] + b1c1) * w2c1;
            t += __shfl_xor(t, 1);
            t += __shfl_xor(t, 2);
            t += __shfl_xor(t, 4);
            t += __shfl_xor(t, 8);
            t += __shfl_xor(t, 16);
            if (l31 == r) {
                int row = rt * 32 + (r & 3) + 8 * (r >> 2) + 4 * half;
                part[wn][row] = t;
            }
        }
    }
    __syncthreads();

    if (tid < NKEYS * 64) {
        int key = tid >> 6, r = tid & 63;
        int gm = m0 + r;
        if (gm < n_atoms) {
            float val = part[2 * key][r] + part[2 * key + 1][r] + b2[key];
            int mol  = find_mol(off, n_mols, gm);
            int mol0 = find_mol(off, n_mols, m0);
            int ml = mol - mol0;
            if (ml < 4) atomicAdd(&molacc[key][ml], val);
            else        atomicAdd(&out[(size_t)key * n_mols + mol], val);
        }
    }
    __syncthreads();

    if (tid < NKEYS * 4) {
        int key = tid >> 2, ml = tid & 3;
        int mol0 = find_mol(off, n_mols, m0);
        int mol = mol0 + ml;
        if (mol < n_mols) {
            float v = molacc[key][ml];
            if (v != 0.0f) atomicAdd(&out[(size_t)key * n_mols + mol], v);
        }
    }
}

extern "C" void kernel_launch(void* const* d_in, const int* in_sizes, int n_in,
                              void* d_out, int out_size, void* d_ws, size_t ws_size,
                              hipStream_t stream) {
    const float* s_i      = (const float*)d_in[0];
    // d_in[1] = xyz: unused by the reference output
    const void*  num_atoms = d_in[2];
    const float* W1 = (const float*)d_in[3];
    const float* b1 = (const float*)d_in[4];
    const float* W2 = (const float*)d_in[5];
    const float* b2 = (const float*)d_in[6];
    int n_atoms = in_sizes[0] / FEAT;
    int n_mols  = in_sizes[2];
    float* out = (float*)d_out;

    int* off = (int*)d_ws;
    size_t off_bytes = (((size_t)(n_mols + 1) * 4) + 255) & ~(size_t)255;
    unsigned short* Bp = (unsigned short*)((char*)d_ws + off_bytes);

    int pack_blocks = (NKEYS * HID * FEAT) / 256;   // 256
    prep_kernel<<<1 + pack_blocks, 256, 0, stream>>>(num_atoms, W1, n_mols, n_atoms,
                                                     off, Bp, out, out_size);

    int gblocks = (n_atoms + 63) / 64;
    gemm_fused<<<gblocks, 256, 0, stream>>>(s_i, Bp, b1, W2, b2, off, out, n_atoms, n_mols);
}